// Round 1
// baseline (1106.046 us; speedup 1.0000x reference)
//
#include <hip/hip_runtime.h>
#include <cstddef>

// Problem constants
#define HH 8
#define FF 512
#define CC 256
#define SS 512
#define BB 64
#define SB (SS*BB)   // 32768

__device__ __forceinline__ float fast_tanh(float x) {
    // tanh(x) = 1 - 2/(e^{2x}+1); handles +-inf saturation correctly.
    float e = __expf(2.0f * x);
    return 1.0f - 2.0f / (e + 1.0f);
}
__device__ __forceinline__ float relu_f(float x) { return fmaxf(x, 0.0f); }

// ---------------------------------------------------------------------------
// K1: fused  d3 = relu(d2@w1 + b1)  [SB, C]   and   tv = tanh(d2@wv) [B,S,C]
// One pass over d2 (67 MB) feeds both GEMMs. Tile 64x64, BK=16, 256 thr.
// ---------------------------------------------------------------------------
__global__ __launch_bounds__(256) void k1_d3_tv(
    const float* __restrict__ d2, const float* __restrict__ w1,
    const float* __restrict__ wv, const float* __restrict__ b1,
    float* __restrict__ d3, float* __restrict__ tv)
{
    __shared__ float As[16][68];
    __shared__ float B1s[16][68];
    __shared__ float B2s[16][68];
    const int r0 = blockIdx.x * 64;
    const int n0 = blockIdx.y * 64;
    const int tid = threadIdx.x;
    const int tx = tid & 15, ty = tid >> 4;
    const int lm = tid >> 2, lk4 = (tid & 3) * 4;   // A staging coords
    const int bk = tid >> 4, bn4 = (tid & 15) * 4;  // B staging coords
    float acc1[4][4] = {};
    float acc2[4][4] = {};
    for (int k0 = 0; k0 < FF; k0 += 16) {
        float4 a = *(const float4*)(d2 + (size_t)(r0 + lm) * FF + k0 + lk4);
        As[lk4+0][lm] = a.x; As[lk4+1][lm] = a.y;
        As[lk4+2][lm] = a.z; As[lk4+3][lm] = a.w;
        *(float4*)&B1s[bk][bn4] = *(const float4*)(w1 + (size_t)(k0+bk)*CC + n0 + bn4);
        *(float4*)&B2s[bk][bn4] = *(const float4*)(wv + (size_t)(k0+bk)*CC + n0 + bn4);
        __syncthreads();
        #pragma unroll
        for (int kk = 0; kk < 16; ++kk) {
            float4 a4  = *(const float4*)&As[kk][ty*4];
            float4 b14 = *(const float4*)&B1s[kk][tx*4];
            float4 b24 = *(const float4*)&B2s[kk][tx*4];
            float av[4]  = {a4.x, a4.y, a4.z, a4.w};
            float bv1[4] = {b14.x, b14.y, b14.z, b14.w};
            float bv2[4] = {b24.x, b24.y, b24.z, b24.w};
            #pragma unroll
            for (int i = 0; i < 4; ++i)
                #pragma unroll
                for (int j = 0; j < 4; ++j) {
                    acc1[i][j] = fmaf(av[i], bv1[j], acc1[i][j]);
                    acc2[i][j] = fmaf(av[i], bv2[j], acc2[i][j]);
                }
        }
        __syncthreads();
    }
    float bias[4];
    #pragma unroll
    for (int j = 0; j < 4; ++j) bias[j] = b1[n0 + tx*4 + j];
    #pragma unroll
    for (int i = 0; i < 4; ++i) {
        int row = r0 + ty*4 + i;        // row = s*B + b
        int s = row >> 6, bb = row & 63;
        float4 o1, o2;
        o1.x = relu_f(acc1[i][0] + bias[0]); o1.y = relu_f(acc1[i][1] + bias[1]);
        o1.z = relu_f(acc1[i][2] + bias[2]); o1.w = relu_f(acc1[i][3] + bias[3]);
        o2.x = fast_tanh(acc2[i][0]); o2.y = fast_tanh(acc2[i][1]);
        o2.z = fast_tanh(acc2[i][2]); o2.w = fast_tanh(acc2[i][3]);
        *(float4*)(d3 + (size_t)row*CC + n0 + tx*4) = o1;
        *(float4*)(tv + ((size_t)bb*SS + s)*CC + n0 + tx*4) = o2;  // tv[b][s][c]
    }
}

// ---------------------------------------------------------------------------
// K2a: d4 = relu(d1@w1 + b1)  [B, C]   (M=64, K=512, N=256 -> 4 blocks)
// ---------------------------------------------------------------------------
__global__ __launch_bounds__(256) void k2a_d4(
    const float* __restrict__ d1, const float* __restrict__ w1,
    const float* __restrict__ b1, float* __restrict__ d4)
{
    __shared__ float As[16][68];
    __shared__ float Bs[16][68];
    const int n0 = blockIdx.x * 64;
    const int tid = threadIdx.x;
    const int tx = tid & 15, ty = tid >> 4;
    const int lm = tid >> 2, lk4 = (tid & 3) * 4;
    const int bk = tid >> 4, bn4 = (tid & 15) * 4;
    float acc[4][4] = {};
    for (int k0 = 0; k0 < FF; k0 += 16) {
        float4 a = *(const float4*)(d1 + (size_t)lm * FF + k0 + lk4);
        As[lk4+0][lm] = a.x; As[lk4+1][lm] = a.y;
        As[lk4+2][lm] = a.z; As[lk4+3][lm] = a.w;
        *(float4*)&Bs[bk][bn4] = *(const float4*)(w1 + (size_t)(k0+bk)*CC + n0 + bn4);
        __syncthreads();
        #pragma unroll
        for (int kk = 0; kk < 16; ++kk) {
            float4 a4 = *(const float4*)&As[kk][ty*4];
            float4 b4 = *(const float4*)&Bs[kk][tx*4];
            float av[4] = {a4.x, a4.y, a4.z, a4.w};
            float bv[4] = {b4.x, b4.y, b4.z, b4.w};
            #pragma unroll
            for (int i = 0; i < 4; ++i)
                #pragma unroll
                for (int j = 0; j < 4; ++j)
                    acc[i][j] = fmaf(av[i], bv[j], acc[i][j]);
        }
        __syncthreads();
    }
    #pragma unroll
    for (int i = 0; i < 4; ++i) {
        int row = ty*4 + i;
        #pragma unroll
        for (int j = 0; j < 4; ++j)
            d4[(size_t)row*CC + n0 + tx*4 + j] = relu_f(acc[i][j] + b1[n0 + tx*4 + j]);
    }
}

// ---------------------------------------------------------------------------
// K2b: e4[h,b,c] = sum_d d4[b,d] * W[h, C+d, c]   (per-head 64x256x256 GEMM)
// ---------------------------------------------------------------------------
__global__ __launch_bounds__(256) void k2b_e4(
    const float* __restrict__ d4, const float* __restrict__ W,
    float* __restrict__ e4)
{
    __shared__ float As[16][68];
    __shared__ float Bs[16][68];
    const int n0 = blockIdx.x * 64;
    const int h  = blockIdx.y;
    const float* Wh = W + ((size_t)h * 2 * CC + CC) * CC;  // rows C..2C-1
    const int tid = threadIdx.x;
    const int tx = tid & 15, ty = tid >> 4;
    const int lm = tid >> 2, lk4 = (tid & 3) * 4;
    const int bk = tid >> 4, bn4 = (tid & 15) * 4;
    float acc[4][4] = {};
    for (int k0 = 0; k0 < CC; k0 += 16) {
        float4 a = *(const float4*)(d4 + (size_t)lm * CC + k0 + lk4);
        As[lk4+0][lm] = a.x; As[lk4+1][lm] = a.y;
        As[lk4+2][lm] = a.z; As[lk4+3][lm] = a.w;
        *(float4*)&Bs[bk][bn4] = *(const float4*)(Wh + (size_t)(k0+bk)*CC + n0 + bn4);
        __syncthreads();
        #pragma unroll
        for (int kk = 0; kk < 16; ++kk) {
            float4 a4 = *(const float4*)&As[kk][ty*4];
            float4 b4 = *(const float4*)&Bs[kk][tx*4];
            float av[4] = {a4.x, a4.y, a4.z, a4.w};
            float bv[4] = {b4.x, b4.y, b4.z, b4.w};
            #pragma unroll
            for (int i = 0; i < 4; ++i)
                #pragma unroll
                for (int j = 0; j < 4; ++j)
                    acc[i][j] = fmaf(av[i], bv[j], acc[i][j]);
        }
        __syncthreads();
    }
    #pragma unroll
    for (int i = 0; i < 4; ++i) {
        int b = ty*4 + i;
        #pragma unroll
        for (int j = 0; j < 4; ++j)
            e4[((size_t)h*BB + b)*CC + n0 + tx*4 + j] = acc[i][j];
    }
}

// ---------------------------------------------------------------------------
// K3: per head: pre = d3 @ W[h][:C]  (full N=256 per block so we can fuse
//     atts[h,b,s] = sum_c P[h,c]*tanh(pre + e4[h,b,c]) without materializing us.
//     Block tile: 64 rows (one s, all b) x 256 cols. Thread: 4 rows x 16 cols.
// ---------------------------------------------------------------------------
__global__ __launch_bounds__(256) void k3_atts(
    const float* __restrict__ d3, const float* __restrict__ W,
    const float* __restrict__ e4, const float* __restrict__ P,
    float* __restrict__ atts)
{
    __shared__ float As[16][68];
    __shared__ float Bs[16][260];
    __shared__ float red[64][17];
    const int h  = blockIdx.y;
    const int r0 = blockIdx.x * 64;         // rows r0..r0+63 share s = blockIdx.x
    const float* Wh = W + (size_t)h * 2 * CC * CC;  // rows 0..C-1
    const int tid = threadIdx.x;
    const int tx = tid & 15, ty = tid >> 4;
    const int lm = tid >> 2, lk4 = (tid & 3) * 4;
    const int bn4 = (tid & 63) * 4, bk0 = tid >> 6;
    float acc[4][16] = {};
    for (int k0 = 0; k0 < CC; k0 += 16) {
        float4 a = *(const float4*)(d3 + (size_t)(r0 + lm) * CC + k0 + lk4);
        As[lk4+0][lm] = a.x; As[lk4+1][lm] = a.y;
        As[lk4+2][lm] = a.z; As[lk4+3][lm] = a.w;
        #pragma unroll
        for (int p = 0; p < 4; ++p) {
            int kk = bk0 + p*4;
            *(float4*)&Bs[kk][bn4] = *(const float4*)(Wh + (size_t)(k0+kk)*CC + bn4);
        }
        __syncthreads();
        #pragma unroll
        for (int kk = 0; kk < 16; ++kk) {
            float4 a4 = *(const float4*)&As[kk][ty*4];
            float av[4] = {a4.x, a4.y, a4.z, a4.w};
            float bvv[16];
            #pragma unroll
            for (int q = 0; q < 4; ++q) {
                float4 b4 = *(const float4*)&Bs[kk][tx*16 + q*4];
                bvv[q*4+0] = b4.x; bvv[q*4+1] = b4.y;
                bvv[q*4+2] = b4.z; bvv[q*4+3] = b4.w;
            }
            #pragma unroll
            for (int i = 0; i < 4; ++i)
                #pragma unroll
                for (int j = 0; j < 16; ++j)
                    acc[i][j] = fmaf(av[i], bvv[j], acc[i][j]);
        }
        __syncthreads();
    }
    // epilogue: tanh + P-reduction over c
    float Pv[16];
    #pragma unroll
    for (int q = 0; q < 4; ++q) {
        float4 p4 = *(const float4*)(P + (size_t)h*CC + tx*16 + q*4);
        Pv[q*4+0] = p4.x; Pv[q*4+1] = p4.y; Pv[q*4+2] = p4.z; Pv[q*4+3] = p4.w;
    }
    #pragma unroll
    for (int i = 0; i < 4; ++i) {
        int b = ty*4 + i;
        const float* e4p = e4 + ((size_t)h*BB + b)*CC + tx*16;
        float part = 0.0f;
        #pragma unroll
        for (int q = 0; q < 4; ++q) {
            float4 ev = *(const float4*)(e4p + q*4);
            float e4v[4] = {ev.x, ev.y, ev.z, ev.w};
            #pragma unroll
            for (int jj = 0; jj < 4; ++jj) {
                float t = fast_tanh(acc[i][q*4+jj] + e4v[jj]);
                part = fmaf(t, Pv[q*4+jj], part);
            }
        }
        red[b][tx] = part;
    }
    __syncthreads();
    if (tid < 64) {
        float ssum = 0.0f;
        #pragma unroll
        for (int t = 0; t < 16; ++t) ssum += red[tid][t];
        int s = blockIdx.x;
        atts[((size_t)h*BB + tid)*SS + s] = ssum;   // atts[h][b][s]
    }
}

// ---------------------------------------------------------------------------
// K4: in-place softmax over s for each (h,b) row of atts  [H*B rows of 512]
// ---------------------------------------------------------------------------
__global__ __launch_bounds__(256) void k4_softmax(float* __restrict__ atts)
{
    const int row = blockIdx.x;
    float* a = atts + (size_t)row * SS;
    const int tid = threadIdx.x;
    __shared__ float red[256];
    float x0 = a[tid], x1 = a[tid + 256];
    red[tid] = fmaxf(x0, x1);
    __syncthreads();
    for (int w = 128; w > 0; w >>= 1) {
        if (tid < w) red[tid] = fmaxf(red[tid], red[tid + w]);
        __syncthreads();
    }
    float m = red[0];
    __syncthreads();
    float e0 = __expf(x0 - m), e1 = __expf(x1 - m);
    red[tid] = e0 + e1;
    __syncthreads();
    for (int w = 128; w > 0; w >>= 1) {
        if (tid < w) red[tid] += red[tid + w];
        __syncthreads();
    }
    float inv = 1.0f / red[0];
    a[tid] = e0 * inv;
    a[tid + 256] = e1 * inv;
}

// ---------------------------------------------------------------------------
// K5: vs[b][h][c] = sum_s scores[h][b][s] * tv[b][s][c]
//     One block per b: stream tv[b] (512 KB) once, scores in LDS.
// ---------------------------------------------------------------------------
__global__ __launch_bounds__(256) void k5_vs(
    const float* __restrict__ scores, const float* __restrict__ tv,
    float* __restrict__ vs)
{
    __shared__ float sc[HH][SS];   // 16 KB
    const int b = blockIdx.x;
    const int tid = threadIdx.x;
    for (int i = tid; i < HH*SS; i += 256) {
        int h = i >> 9, s = i & 511;
        sc[h][s] = scores[((size_t)h*BB + b)*SS + s];
    }
    __syncthreads();
    const float* tvb = tv + (size_t)b * SS * CC;
    const int c = tid;   // 256 threads <-> 256 c
    float acc[HH] = {};
    #pragma unroll 8
    for (int s = 0; s < SS; ++s) {
        float x = tvb[(size_t)s*CC + c];
        #pragma unroll
        for (int h = 0; h < HH; ++h)
            acc[h] = fmaf(sc[h][s], x, acc[h]);
    }
    #pragma unroll
    for (int h = 0; h < HH; ++h)
        vs[((size_t)b*HH + h)*CC + c] = acc[h];   // [b][h*C+c] flat
}

// ---------------------------------------------------------------------------
// K6: out = relu(vs_flat @ wcc + bcc)   [64 x 2048] @ [2048 x 128]
// ---------------------------------------------------------------------------
__global__ __launch_bounds__(256) void k6_out(
    const float* __restrict__ vs, const float* __restrict__ wcc,
    const float* __restrict__ bcc, float* __restrict__ out)
{
    __shared__ float As[16][68];
    __shared__ float Bs[16][68];
    const int n0 = blockIdx.x * 64;
    const int tid = threadIdx.x;
    const int tx = tid & 15, ty = tid >> 4;
    const int lm = tid >> 2, lk4 = (tid & 3) * 4;
    const int bk = tid >> 4, bn4 = (tid & 15) * 4;
    float acc[4][4] = {};
    const int K = HH * CC;  // 2048
    for (int k0 = 0; k0 < K; k0 += 16) {
        float4 a = *(const float4*)(vs + (size_t)lm * K + k0 + lk4);
        As[lk4+0][lm] = a.x; As[lk4+1][lm] = a.y;
        As[lk4+2][lm] = a.z; As[lk4+3][lm] = a.w;
        *(float4*)&Bs[bk][bn4] = *(const float4*)(wcc + (size_t)(k0+bk)*128 + n0 + bn4);
        __syncthreads();
        #pragma unroll
        for (int kk = 0; kk < 16; ++kk) {
            float4 a4 = *(const float4*)&As[kk][ty*4];
            float4 b4 = *(const float4*)&Bs[kk][tx*4];
            float av[4] = {a4.x, a4.y, a4.z, a4.w};
            float bv[4] = {b4.x, b4.y, b4.z, b4.w};
            #pragma unroll
            for (int i = 0; i < 4; ++i)
                #pragma unroll
                for (int j = 0; j < 4; ++j)
                    acc[i][j] = fmaf(av[i], bv[j], acc[i][j]);
        }
        __syncthreads();
    }
    #pragma unroll
    for (int i = 0; i < 4; ++i) {
        int row = ty*4 + i;
        #pragma unroll
        for (int j = 0; j < 4; ++j)
            out[(size_t)row*128 + n0 + tx*4 + j] =
                relu_f(acc[i][j] + bcc[n0 + tx*4 + j]);
    }
}

// ---------------------------------------------------------------------------
extern "C" void kernel_launch(void* const* d_in, const int* in_sizes, int n_in,
                              void* d_out, int out_size, void* d_ws, size_t ws_size,
                              hipStream_t stream)
{
    (void)in_sizes; (void)n_in; (void)out_size; (void)ws_size;
    const float* d1  = (const float*)d_in[0];
    const float* d2  = (const float*)d_in[1];
    const float* w1  = (const float*)d_in[2];
    const float* b1  = (const float*)d_in[3];
    const float* W   = (const float*)d_in[4];
    const float* P   = (const float*)d_in[5];
    const float* wv  = (const float*)d_in[6];
    const float* wcc = (const float*)d_in[7];
    const float* bcc = (const float*)d_in[8];
    // d_in[9] = d2_size (static 512), ignored.
    float* out = (float*)d_out;

    // Workspace layout (floats). Total ~66.1 MB.
    float* ws   = (float*)d_ws;
    float* d3   = ws;                            // SB*C       = 8388608
    float* tv   = d3   + (size_t)SB * CC;        // B*S*C      = 8388608
    float* d4   = tv   + (size_t)BB * SS * CC;   // B*C        = 16384
    float* e4   = d4   + (size_t)BB * CC;        // H*B*C      = 131072
    float* atts = e4   + (size_t)HH * BB * CC;   // H*B*S      = 262144
    float* vs   = atts + (size_t)HH * BB * SS;   // B*H*C      = 131072

    k1_d3_tv <<<dim3(SB/64, CC/64), 256, 0, stream>>>(d2, w1, wv, b1, d3, tv);
    k2a_d4   <<<dim3(CC/64),        256, 0, stream>>>(d1, w1, b1, d4);
    k2b_e4   <<<dim3(CC/64, HH),    256, 0, stream>>>(d4, W, e4);
    k3_atts  <<<dim3(SS, HH),       256, 0, stream>>>(d3, W, e4, P, atts);
    k4_softmax<<<dim3(HH*BB),       256, 0, stream>>>(atts);
    k5_vs    <<<dim3(BB),           256, 0, stream>>>(atts, tv, vs);
    k6_out   <<<dim3(128/64),       256, 0, stream>>>(vs, wcc, bcc, out);
}

// Round 3
// 550.770 us; speedup vs baseline: 2.0082x; 2.0082x over previous
//
#include <hip/hip_runtime.h>
#include <cstddef>
#include <cstdint>

// Problem constants
#define HH 8
#define FF 512
#define CC 256
#define SS 512
#define BB 64
#define SB (SS*BB)   // 32768

typedef __attribute__((ext_vector_type(4))) float f32x4;
typedef __attribute__((ext_vector_type(8))) short bf16x8;

__device__ __forceinline__ float fast_tanh(float x) {
    float e = __expf(2.0f * x);
    return 1.0f - 2.0f / (e + 1.0f);
}
__device__ __forceinline__ float relu_f(float x) { return fmaxf(x, 0.0f); }

// bf16 bit helpers (round-to-nearest-even)
__device__ __forceinline__ unsigned short f2bf(float x) {
    unsigned u = __float_as_uint(x);
    unsigned r = u + 0x7FFFu + ((u >> 16) & 1u);
    return (unsigned short)(r >> 16);
}
__device__ __forceinline__ float bf2f(unsigned short h) {
    return __uint_as_float(((unsigned)h) << 16);
}

// ---------------------------------------------------------------------------
// P1: transpose+split w1 -> w1t_hi/lo [n=256][k=512], wv -> wvt_hi/lo
// ---------------------------------------------------------------------------
__global__ __launch_bounds__(256) void p_w1wv(
    const float* __restrict__ w1, const float* __restrict__ wv,
    unsigned short* __restrict__ w1t_hi, unsigned short* __restrict__ w1t_lo,
    unsigned short* __restrict__ wvt_hi, unsigned short* __restrict__ wvt_lo)
{
    int id = blockIdx.x * 256 + threadIdx.x;   // 0 .. 131071
    int n = id >> 9, k = id & 511;
    float x = w1[(size_t)k * CC + n];
    unsigned short hx = f2bf(x);
    w1t_hi[id] = hx;
    w1t_lo[id] = f2bf(x - bf2f(hx));
    float y = wv[(size_t)k * CC + n];
    unsigned short hy = f2bf(y);
    wvt_hi[id] = hy;
    wvt_lo[id] = f2bf(y - bf2f(hy));
}

// ---------------------------------------------------------------------------
// P2: transpose+split first-C rows of W: Wt_hi/lo [h][n=256][k=256]
// ---------------------------------------------------------------------------
__global__ __launch_bounds__(256) void p_W(
    const float* __restrict__ W,
    unsigned short* __restrict__ Wt_hi, unsigned short* __restrict__ Wt_lo)
{
    int id = blockIdx.x * 256 + threadIdx.x;   // 0 .. 524287
    int h = id >> 16, n = (id >> 8) & 255, k = id & 255;
    float x = W[((size_t)h * 2 * CC + k) * CC + n];   // rows 0..C-1
    unsigned short hx = f2bf(x);
    Wt_hi[id] = hx;
    Wt_lo[id] = f2bf(x - bf2f(hx));
}

// ---------------------------------------------------------------------------
// K1a: d3 = relu(d2@w1 + b1), stored split bf16 hi/lo [SB][C].
// MFMA 16x16x32, 3-term split. Block: M=64 x N=256 full, 4 waves (waveM=16).
// ---------------------------------------------------------------------------
__global__ __launch_bounds__(256) void k1a_d3(
    const float* __restrict__ d2,
    const unsigned short* __restrict__ w1t_hi, const unsigned short* __restrict__ w1t_lo,
    const float* __restrict__ b1,
    unsigned short* __restrict__ d3_hi, unsigned short* __restrict__ d3_lo)
{
    __shared__ __align__(16) unsigned short A_hi[64][32];
    __shared__ __align__(16) unsigned short A_lo[64][32];
    __shared__ __align__(16) unsigned short B_hi[256][32];
    __shared__ __align__(16) unsigned short B_lo[256][32];
    __shared__ float bls[256];

    const int tid = threadIdx.x;
    const int lane = tid & 63, w = tid >> 6;
    const int r0 = blockIdx.x * 64;
    const int m0 = w * 16;
    bls[tid] = b1[tid];

    f32x4 zero = {0.0f, 0.0f, 0.0f, 0.0f};
    f32x4 acc[16];
    #pragma unroll
    for (int t = 0; t < 16; ++t) acc[t] = zero;

    const int srow = tid >> 2, skp = (tid & 3) * 8;   // A staging coords

    for (int k0 = 0; k0 < FF; k0 += 32) {
        // stage A: load fp32, split to hi/lo
        {
            const float* src = d2 + (size_t)(r0 + srow) * FF + k0 + skp;
            float v[8];
            *(float4*)&v[0] = *(const float4*)src;
            *(float4*)&v[4] = *(const float4*)(src + 4);
            bf16x8 vh, vl;
            #pragma unroll
            for (int j = 0; j < 8; ++j) {
                unsigned short h = f2bf(v[j]);
                vh[j] = (short)h;
                vl[j] = (short)f2bf(v[j] - bf2f(h));
            }
            *(bf16x8*)&A_hi[srow][skp] = vh;
            *(bf16x8*)&A_lo[srow][skp] = vl;
            // stage B: 256n x 32k = 8192 shorts = 1024 bf16x8 stores -> j<4
            #pragma unroll
            for (int j = 0; j < 4; ++j) {
                int idx = j * 256 + tid;
                int n = idx >> 2, kp = (idx & 3) * 8;
                *(bf16x8*)&B_hi[n][kp] = *(const bf16x8*)(w1t_hi + (size_t)n * FF + k0 + kp);
                *(bf16x8*)&B_lo[n][kp] = *(const bf16x8*)(w1t_lo + (size_t)n * FF + k0 + kp);
            }
        }
        __syncthreads();
        bf16x8 ah = *(bf16x8*)&A_hi[m0 + (lane & 15)][(lane >> 4) * 8];
        bf16x8 al = *(bf16x8*)&A_lo[m0 + (lane & 15)][(lane >> 4) * 8];
        #pragma unroll
        for (int t = 0; t < 16; ++t) {
            bf16x8 bh = *(bf16x8*)&B_hi[t * 16 + (lane & 15)][(lane >> 4) * 8];
            bf16x8 bl = *(bf16x8*)&B_lo[t * 16 + (lane & 15)][(lane >> 4) * 8];
            acc[t] = __builtin_amdgcn_mfma_f32_16x16x32_bf16(ah, bh, acc[t], 0, 0, 0);
            acc[t] = __builtin_amdgcn_mfma_f32_16x16x32_bf16(ah, bl, acc[t], 0, 0, 0);
            acc[t] = __builtin_amdgcn_mfma_f32_16x16x32_bf16(al, bh, acc[t], 0, 0, 0);
        }
        __syncthreads();
    }
    // epilogue: bias + relu + split store. C-layout: col=lane&15, row=(lane>>4)*4+reg
    const int cb = lane & 15, g = lane >> 4;
    #pragma unroll
    for (int t = 0; t < 16; ++t) {
        int c = t * 16 + cb;
        float bias = bls[c];
        #pragma unroll
        for (int r = 0; r < 4; ++r) {
            int gr = r0 + m0 + g * 4 + r;
            float val = relu_f(acc[t][r] + bias);
            unsigned short hv = f2bf(val);
            d3_hi[(size_t)gr * CC + c] = hv;
            d3_lo[(size_t)gr * CC + c] = f2bf(val - bf2f(hv));
        }
    }
}

// ---------------------------------------------------------------------------
// K1b: tv[b][s][c] = bf16(tanh(d2@wv)). 3-term split.
// ---------------------------------------------------------------------------
__global__ __launch_bounds__(256) void k1b_tv(
    const float* __restrict__ d2,
    const unsigned short* __restrict__ wvt_hi, const unsigned short* __restrict__ wvt_lo,
    unsigned short* __restrict__ tv)
{
    __shared__ __align__(16) unsigned short A_hi[64][32];
    __shared__ __align__(16) unsigned short A_lo[64][32];
    __shared__ __align__(16) unsigned short B_hi[256][32];
    __shared__ __align__(16) unsigned short B_lo[256][32];

    const int tid = threadIdx.x;
    const int lane = tid & 63, w = tid >> 6;
    const int r0 = blockIdx.x * 64;
    const int m0 = w * 16;
    const int s = blockIdx.x;       // rows r0..r0+63 share s

    f32x4 zero = {0.0f, 0.0f, 0.0f, 0.0f};
    f32x4 acc[16];
    #pragma unroll
    for (int t = 0; t < 16; ++t) acc[t] = zero;

    const int srow = tid >> 2, skp = (tid & 3) * 8;

    for (int k0 = 0; k0 < FF; k0 += 32) {
        {
            const float* src = d2 + (size_t)(r0 + srow) * FF + k0 + skp;
            float v[8];
            *(float4*)&v[0] = *(const float4*)src;
            *(float4*)&v[4] = *(const float4*)(src + 4);
            bf16x8 vh, vl;
            #pragma unroll
            for (int j = 0; j < 8; ++j) {
                unsigned short h = f2bf(v[j]);
                vh[j] = (short)h;
                vl[j] = (short)f2bf(v[j] - bf2f(h));
            }
            *(bf16x8*)&A_hi[srow][skp] = vh;
            *(bf16x8*)&A_lo[srow][skp] = vl;
            #pragma unroll
            for (int j = 0; j < 4; ++j) {
                int idx = j * 256 + tid;
                int n = idx >> 2, kp = (idx & 3) * 8;
                *(bf16x8*)&B_hi[n][kp] = *(const bf16x8*)(wvt_hi + (size_t)n * FF + k0 + kp);
                *(bf16x8*)&B_lo[n][kp] = *(const bf16x8*)(wvt_lo + (size_t)n * FF + k0 + kp);
            }
        }
        __syncthreads();
        bf16x8 ah = *(bf16x8*)&A_hi[m0 + (lane & 15)][(lane >> 4) * 8];
        bf16x8 al = *(bf16x8*)&A_lo[m0 + (lane & 15)][(lane >> 4) * 8];
        #pragma unroll
        for (int t = 0; t < 16; ++t) {
            bf16x8 bh = *(bf16x8*)&B_hi[t * 16 + (lane & 15)][(lane >> 4) * 8];
            bf16x8 bl = *(bf16x8*)&B_lo[t * 16 + (lane & 15)][(lane >> 4) * 8];
            acc[t] = __builtin_amdgcn_mfma_f32_16x16x32_bf16(ah, bh, acc[t], 0, 0, 0);
            acc[t] = __builtin_amdgcn_mfma_f32_16x16x32_bf16(ah, bl, acc[t], 0, 0, 0);
            acc[t] = __builtin_amdgcn_mfma_f32_16x16x32_bf16(al, bh, acc[t], 0, 0, 0);
        }
        __syncthreads();
    }
    const int cb = lane & 15, g = lane >> 4;
    #pragma unroll
    for (int t = 0; t < 16; ++t) {
        int c = t * 16 + cb;
        #pragma unroll
        for (int r = 0; r < 4; ++r) {
            int b = m0 + g * 4 + r;                  // local row = b
            tv[((size_t)b * SS + s) * CC + c] = f2bf(fast_tanh(acc[t][r]));
        }
    }
}

// ---------------------------------------------------------------------------
// K2a: d4 = relu(d1@w1 + b1)  [B, C]  (fp32 vector, tiny)
// ---------------------------------------------------------------------------
__global__ __launch_bounds__(256) void k2a_d4(
    const float* __restrict__ d1, const float* __restrict__ w1,
    const float* __restrict__ b1, float* __restrict__ d4)
{
    __shared__ float As[16][68];
    __shared__ float Bs[16][68];
    const int n0 = blockIdx.x * 64;
    const int tid = threadIdx.x;
    const int tx = tid & 15, ty = tid >> 4;
    const int lm = tid >> 2, lk4 = (tid & 3) * 4;
    const int bk = tid >> 4, bn4 = (tid & 15) * 4;
    float acc[4][4] = {};
    for (int k0 = 0; k0 < FF; k0 += 16) {
        float4 a = *(const float4*)(d1 + (size_t)lm * FF + k0 + lk4);
        As[lk4+0][lm] = a.x; As[lk4+1][lm] = a.y;
        As[lk4+2][lm] = a.z; As[lk4+3][lm] = a.w;
        *(float4*)&Bs[bk][bn4] = *(const float4*)(w1 + (size_t)(k0+bk)*CC + n0 + bn4);
        __syncthreads();
        #pragma unroll
        for (int kk = 0; kk < 16; ++kk) {
            float4 a4 = *(const float4*)&As[kk][ty*4];
            float4 b4 = *(const float4*)&Bs[kk][tx*4];
            float av[4] = {a4.x, a4.y, a4.z, a4.w};
            float bv[4] = {b4.x, b4.y, b4.z, b4.w};
            #pragma unroll
            for (int i = 0; i < 4; ++i)
                #pragma unroll
                for (int j = 0; j < 4; ++j)
                    acc[i][j] = fmaf(av[i], bv[j], acc[i][j]);
        }
        __syncthreads();
    }
    #pragma unroll
    for (int i = 0; i < 4; ++i) {
        int row = ty*4 + i;
        #pragma unroll
        for (int j = 0; j < 4; ++j)
            d4[(size_t)row*CC + n0 + tx*4 + j] = relu_f(acc[i][j] + b1[n0 + tx*4 + j]);
    }
}

// ---------------------------------------------------------------------------
// K2b: e4[h,b,c] = sum_d d4[b,d] * W[h, C+d, c]  (fp32 vector, tiny)
// ---------------------------------------------------------------------------
__global__ __launch_bounds__(256) void k2b_e4(
    const float* __restrict__ d4, const float* __restrict__ W,
    float* __restrict__ e4)
{
    __shared__ float As[16][68];
    __shared__ float Bs[16][68];
    const int n0 = blockIdx.x * 64;
    const int h  = blockIdx.y;
    const float* Wh = W + ((size_t)h * 2 * CC + CC) * CC;
    const int tid = threadIdx.x;
    const int tx = tid & 15, ty = tid >> 4;
    const int lm = tid >> 2, lk4 = (tid & 3) * 4;
    const int bk = tid >> 4, bn4 = (tid & 15) * 4;
    float acc[4][4] = {};
    for (int k0 = 0; k0 < CC; k0 += 16) {
        float4 a = *(const float4*)(d4 + (size_t)lm * CC + k0 + lk4);
        As[lk4+0][lm] = a.x; As[lk4+1][lm] = a.y;
        As[lk4+2][lm] = a.z; As[lk4+3][lm] = a.w;
        *(float4*)&Bs[bk][bn4] = *(const float4*)(Wh + (size_t)(k0+bk)*CC + n0 + bn4);
        __syncthreads();
        #pragma unroll
        for (int kk = 0; kk < 16; ++kk) {
            float4 a4 = *(const float4*)&As[kk][ty*4];
            float4 b4 = *(const float4*)&Bs[kk][tx*4];
            float av[4] = {a4.x, a4.y, a4.z, a4.w};
            float bv[4] = {b4.x, b4.y, b4.z, b4.w};
            #pragma unroll
            for (int i = 0; i < 4; ++i)
                #pragma unroll
                for (int j = 0; j < 4; ++j)
                    acc[i][j] = fmaf(av[i], bv[j], acc[i][j]);
        }
        __syncthreads();
    }
    #pragma unroll
    for (int i = 0; i < 4; ++i) {
        int b = ty*4 + i;
        #pragma unroll
        for (int j = 0; j < 4; ++j)
            e4[((size_t)h*BB + b)*CC + n0 + tx*4 + j] = acc[i][j];
    }
}

// ---------------------------------------------------------------------------
// K3: atts[h,b,s] = sum_c P[h,c] * tanh( (d3 @ Wt[h])[row,c] + e4[h,b,c] )
// MFMA 3-term split. Block: M=64 (one s, all b) x N=256 full, 4 waves.
// ---------------------------------------------------------------------------
__global__ __launch_bounds__(256) void k3_atts(
    const unsigned short* __restrict__ d3_hi, const unsigned short* __restrict__ d3_lo,
    const unsigned short* __restrict__ Wt_hi, const unsigned short* __restrict__ Wt_lo,
    const float* __restrict__ e4, const float* __restrict__ P,
    float* __restrict__ atts)
{
    __shared__ __align__(16) unsigned short A_hi[64][32];
    __shared__ __align__(16) unsigned short A_lo[64][32];
    __shared__ __align__(16) unsigned short B_hi[256][32];
    __shared__ __align__(16) unsigned short B_lo[256][32];
    __shared__ float pf[256];

    const int tid = threadIdx.x;
    const int lane = tid & 63, w = tid >> 6;
    const int h = blockIdx.y;
    const int r0 = blockIdx.x * 64;
    const int s = blockIdx.x;
    const int m0 = w * 16;
    pf[tid] = P[(size_t)h * CC + tid];

    const unsigned short* WhH = Wt_hi + (size_t)h * CC * CC;
    const unsigned short* WhL = Wt_lo + (size_t)h * CC * CC;

    f32x4 zero = {0.0f, 0.0f, 0.0f, 0.0f};
    f32x4 acc[16];
    #pragma unroll
    for (int t = 0; t < 16; ++t) acc[t] = zero;

    const int srow = tid >> 2, skp = (tid & 3) * 8;

    for (int k0 = 0; k0 < CC; k0 += 32) {
        *(bf16x8*)&A_hi[srow][skp] = *(const bf16x8*)(d3_hi + (size_t)(r0 + srow) * CC + k0 + skp);
        *(bf16x8*)&A_lo[srow][skp] = *(const bf16x8*)(d3_lo + (size_t)(r0 + srow) * CC + k0 + skp);
        #pragma unroll
        for (int j = 0; j < 4; ++j) {
            int idx = j * 256 + tid;
            int n = idx >> 2, kp = (idx & 3) * 8;
            *(bf16x8*)&B_hi[n][kp] = *(const bf16x8*)(WhH + (size_t)n * CC + k0 + kp);
            *(bf16x8*)&B_lo[n][kp] = *(const bf16x8*)(WhL + (size_t)n * CC + k0 + kp);
        }
        __syncthreads();
        bf16x8 ah = *(bf16x8*)&A_hi[m0 + (lane & 15)][(lane >> 4) * 8];
        bf16x8 al = *(bf16x8*)&A_lo[m0 + (lane & 15)][(lane >> 4) * 8];
        #pragma unroll
        for (int t = 0; t < 16; ++t) {
            bf16x8 bh = *(bf16x8*)&B_hi[t * 16 + (lane & 15)][(lane >> 4) * 8];
            bf16x8 bl = *(bf16x8*)&B_lo[t * 16 + (lane & 15)][(lane >> 4) * 8];
            acc[t] = __builtin_amdgcn_mfma_f32_16x16x32_bf16(ah, bh, acc[t], 0, 0, 0);
            acc[t] = __builtin_amdgcn_mfma_f32_16x16x32_bf16(ah, bl, acc[t], 0, 0, 0);
            acc[t] = __builtin_amdgcn_mfma_f32_16x16x32_bf16(al, bh, acc[t], 0, 0, 0);
        }
        __syncthreads();
    }
    // epilogue: tanh + P-reduce over c (cols), rows are b
    const int cb = lane & 15, g = lane >> 4;
    float part[4] = {0.0f, 0.0f, 0.0f, 0.0f};
    #pragma unroll
    for (int t = 0; t < 16; ++t) {
        int c = t * 16 + cb;
        float p = pf[c];
        #pragma unroll
        for (int r = 0; r < 4; ++r) {
            int b = m0 + g * 4 + r;
            float u = acc[t][r] + e4[((size_t)h * BB + b) * CC + c];
            part[r] = fmaf(p, fast_tanh(u), part[r]);
        }
    }
    #pragma unroll
    for (int r = 0; r < 4; ++r) {
        float v = part[r];
        v += __shfl_xor(v, 1); v += __shfl_xor(v, 2);
        v += __shfl_xor(v, 4); v += __shfl_xor(v, 8);
        if (cb == 0) {
            int b = m0 + g * 4 + r;
            atts[((size_t)h * BB + b) * SS + s] = v;
        }
    }
}

// ---------------------------------------------------------------------------
// K4: softmax over s for each (h,b) row of atts
// ---------------------------------------------------------------------------
__global__ __launch_bounds__(256) void k4_softmax(float* __restrict__ atts)
{
    const int row = blockIdx.x;
    float* a = atts + (size_t)row * SS;
    const int tid = threadIdx.x;
    __shared__ float red[256];
    float x0 = a[tid], x1 = a[tid + 256];
    red[tid] = fmaxf(x0, x1);
    __syncthreads();
    for (int w = 128; w > 0; w >>= 1) {
        if (tid < w) red[tid] = fmaxf(red[tid], red[tid + w]);
        __syncthreads();
    }
    float m = red[0];
    __syncthreads();
    float e0 = __expf(x0 - m), e1 = __expf(x1 - m);
    red[tid] = e0 + e1;
    __syncthreads();
    for (int w = 128; w > 0; w >>= 1) {
        if (tid < w) red[tid] += red[tid + w];
        __syncthreads();
    }
    float inv = 1.0f / red[0];
    a[tid] = e0 * inv;
    a[tid + 256] = e1 * inv;
}

// ---------------------------------------------------------------------------
// K5: vs[b][h][c] = sum_s scores[h][b][s] * tv[b][s][c]   (tv is bf16)
// ---------------------------------------------------------------------------
__global__ __launch_bounds__(256) void k5_vs(
    const float* __restrict__ scores, const unsigned short* __restrict__ tv,
    float* __restrict__ vs)
{
    __shared__ float sc[HH][SS];   // 16 KB
    const int b = blockIdx.x;
    const int tid = threadIdx.x;
    for (int i = tid; i < HH*SS; i += 256) {
        int h = i >> 9, s = i & 511;
        sc[h][s] = scores[((size_t)h*BB + b)*SS + s];
    }
    __syncthreads();
    const unsigned short* tvb = tv + (size_t)b * SS * CC;
    const int c = tid;
    float acc[HH] = {};
    #pragma unroll 8
    for (int s = 0; s < SS; ++s) {
        float x = bf2f(tvb[(size_t)s*CC + c]);
        #pragma unroll
        for (int h = 0; h < HH; ++h)
            acc[h] = fmaf(sc[h][s], x, acc[h]);
    }
    #pragma unroll
    for (int h = 0; h < HH; ++h)
        vs[((size_t)b*HH + h)*CC + c] = acc[h];
}

// ---------------------------------------------------------------------------
// K6: out = relu(vs_flat @ wcc + bcc)   [64 x 2048] @ [2048 x 128]
// ---------------------------------------------------------------------------
__global__ __launch_bounds__(256) void k6_out(
    const float* __restrict__ vs, const float* __restrict__ wcc,
    const float* __restrict__ bcc, float* __restrict__ out)
{
    __shared__ float As[16][68];
    __shared__ float Bs[16][68];
    const int n0 = blockIdx.x * 64;
    const int tid = threadIdx.x;
    const int tx = tid & 15, ty = tid >> 4;
    const int lm = tid >> 2, lk4 = (tid & 3) * 4;
    const int bk = tid >> 4, bn4 = (tid & 15) * 4;
    float acc[4][4] = {};
    const int K = HH * CC;  // 2048
    for (int k0 = 0; k0 < K; k0 += 16) {
        float4 a = *(const float4*)(vs + (size_t)lm * K + k0 + lk4);
        As[lk4+0][lm] = a.x; As[lk4+1][lm] = a.y;
        As[lk4+2][lm] = a.z; As[lk4+3][lm] = a.w;
        *(float4*)&Bs[bk][bn4] = *(const float4*)(wcc + (size_t)(k0+bk)*128 + n0 + bn4);
        __syncthreads();
        #pragma unroll
        for (int kk = 0; kk < 16; ++kk) {
            float4 a4 = *(const float4*)&As[kk][ty*4];
            float4 b4 = *(const float4*)&Bs[kk][tx*4];
            float av[4] = {a4.x, a4.y, a4.z, a4.w};
            float bv[4] = {b4.x, b4.y, b4.z, b4.w};
            #pragma unroll
            for (int i = 0; i < 4; ++i)
                #pragma unroll
                for (int j = 0; j < 4; ++j)
                    acc[i][j] = fmaf(av[i], bv[j], acc[i][j]);
        }
        __syncthreads();
    }
    #pragma unroll
    for (int i = 0; i < 4; ++i) {
        int row = ty*4 + i;
        #pragma unroll
        for (int j = 0; j < 4; ++j)
            out[(size_t)row*128 + n0 + tx*4 + j] =
                relu_f(acc[i][j] + bcc[n0 + tx*4 + j]);
    }
}

// ---------------------------------------------------------------------------
extern "C" void kernel_launch(void* const* d_in, const int* in_sizes, int n_in,
                              void* d_out, int out_size, void* d_ws, size_t ws_size,
                              hipStream_t stream)
{
    (void)in_sizes; (void)n_in; (void)out_size; (void)ws_size;
    const float* d1  = (const float*)d_in[0];
    const float* d2  = (const float*)d_in[1];
    const float* w1  = (const float*)d_in[2];
    const float* b1  = (const float*)d_in[3];
    const float* W   = (const float*)d_in[4];
    const float* P   = (const float*)d_in[5];
    const float* wv  = (const float*)d_in[6];
    const float* wcc = (const float*)d_in[7];
    const float* bcc = (const float*)d_in[8];
    float* out = (float*)d_out;

    // Workspace layout (bytes): ~55 MB total
    char* p = (char*)d_ws;
    unsigned short* d3_hi = (unsigned short*)p;  p += (size_t)SB * CC * 2;        // 16.78 MB
    unsigned short* d3_lo = (unsigned short*)p;  p += (size_t)SB * CC * 2;        // 16.78 MB
    unsigned short* tv    = (unsigned short*)p;  p += (size_t)BB * SS * CC * 2;   // 16.78 MB
    unsigned short* w1t_hi = (unsigned short*)p; p += (size_t)CC * FF * 2;        // 256 KB
    unsigned short* w1t_lo = (unsigned short*)p; p += (size_t)CC * FF * 2;
    unsigned short* wvt_hi = (unsigned short*)p; p += (size_t)CC * FF * 2;
    unsigned short* wvt_lo = (unsigned short*)p; p += (size_t)CC * FF * 2;
    unsigned short* Wt_hi  = (unsigned short*)p; p += (size_t)HH * CC * CC * 2;   // 1 MB
    unsigned short* Wt_lo  = (unsigned short*)p; p += (size_t)HH * CC * CC * 2;
    float* d4   = (float*)p;  p += (size_t)BB * CC * 4;        // 64 KB
    float* e4   = (float*)p;  p += (size_t)HH * BB * CC * 4;   // 512 KB
    float* atts = (float*)p;  p += (size_t)HH * BB * SS * 4;   // 1 MB
    float* vs   = (float*)p;  p += (size_t)BB * HH * CC * 4;   // 512 KB

    p_w1wv   <<<dim3(512),          256, 0, stream>>>(w1, wv, w1t_hi, w1t_lo, wvt_hi, wvt_lo);
    p_W      <<<dim3(2048),         256, 0, stream>>>(W, Wt_hi, Wt_lo);
    k2a_d4   <<<dim3(CC/64),        256, 0, stream>>>(d1, w1, b1, d4);
    k2b_e4   <<<dim3(CC/64, HH),    256, 0, stream>>>(d4, W, e4);
    k1a_d3   <<<dim3(SB/64),        256, 0, stream>>>(d2, w1t_hi, w1t_lo, b1, d3_hi, d3_lo);
    k1b_tv   <<<dim3(SB/64),        256, 0, stream>>>(d2, wvt_hi, wvt_lo, tv);
    k3_atts  <<<dim3(SS, HH),       256, 0, stream>>>(d3_hi, d3_lo, Wt_hi, Wt_lo, e4, P, atts);
    k4_softmax<<<dim3(HH*BB),       256, 0, stream>>>(atts);
    k5_vs    <<<dim3(BB),           256, 0, stream>>>(atts, tv, vs);
    k6_out   <<<dim3(128/64),       256, 0, stream>>>(vs, wcc, bcc, out);
}